// Round 4
// baseline (5138.434 us; speedup 1.0000x reference)
//
#include <hip/hip_runtime.h>
#include <hip/hip_cooperative_groups.h>
#include <math.h>
#include <stdint.h>

namespace cg = cooperative_groups;

namespace {

constexpr int NROW = 16384;   // B*A
constexpr int NF   = 512;     // n_in
constexpr int MIND = 2048;    // inducing points
constexpr float CC = 0.98f;   // centering constant: Kx = exp(-d), d ~ 0.004

typedef _Float16 half8 __attribute__((ext_vector_type(8)));
typedef float floatx4 __attribute__((ext_vector_type(4)));

__device__ __forceinline__ void gload16(const void* g, void* l) {
  __builtin_amdgcn_global_load_lds(
      (__attribute__((address_space(1))) void*)g,
      (__attribute__((address_space(3))) void*)l, 16, 0, 0);
}

// ---------------------------------------------------------------- stats ----
__global__ __launch_bounds__(256) void stats_kernel(
    const float* __restrict__ x, const int* __restrict__ mask,
    float* __restrict__ sum, float* __restrict__ sumsq, float* __restrict__ cnt)
{
  const int t = threadIdx.x;
  const int row0 = blockIdx.x * 64;
  float s0 = 0.f, s1 = 0.f, q0 = 0.f, q1 = 0.f, c = 0.f;
  for (int r = 0; r < 64; ++r) {
    const int row = row0 + r;
    const float m = (mask[row] != 0) ? 1.f : 0.f;
    const float v0 = x[(size_t)row * NF + t];
    const float v1 = x[(size_t)row * NF + t + 256];
    s0 += m * v0; q0 += m * v0 * v0;
    s1 += m * v1; q1 += m * v1 * v1;
    c += m;
  }
  atomicAdd(&sum[t], s0);        atomicAdd(&sum[t + 256], s1);
  atomicAdd(&sumsq[t], q0);      atomicAdd(&sumsq[t + 256], q1);
  if (t == 0) atomicAdd(cnt, c);
}

__global__ __launch_bounds__(256) void finalize_stats(
    const float* __restrict__ sum, const float* __restrict__ sumsq,
    const float* __restrict__ cnt, const float* __restrict__ gamma,
    float* __restrict__ meanv, float* __restrict__ stdv,
    float* __restrict__ zsv, float* __restrict__ giv)
{
  const int f = blockIdx.x * 256 + threadIdx.x;   // <<<2,256>>>
  const float n = cnt[0];
  const float mu = sum[f] / n;
  const float var = (sumsq[f] - sum[f] * mu) / (n - 1.0f);
  const float sd = sqrtf(var) + 1e-5f;
  const float g = gamma[f];
  const float g2 = g * g + 0.001f;
  meanv[f] = mu;
  stdv[f]  = sd;
  zsv[f]   = 1.0f / (sd * g2);
  giv[f]   = 1.0f / g2;
}

// z rows (masked, normalized, /g2) fp16 + zi rows fp16 + fp32 norms of the
// fp16-ROUNDED values (so d_jj ~ 0 exactly)
__global__ __launch_bounds__(256) void make_z(
    const float* __restrict__ x, const int* __restrict__ mask,
    const float* __restrict__ ip, const float* __restrict__ meanv,
    const float* __restrict__ zsv, const float* __restrict__ giv,
    _Float16* __restrict__ Zh, _Float16* __restrict__ Zih,
    float* __restrict__ rnorm, float* __restrict__ cnorm)
{
  const int row = blockIdx.x;
  const int t = threadIdx.x;
  float v0, v1;
  if (row < NROW) {
    const float m = (mask[row] != 0) ? 1.f : 0.f;
    v0 = (x[(size_t)row * NF + t      ] - meanv[t      ]) * zsv[t      ] * m;
    v1 = (x[(size_t)row * NF + t + 256] - meanv[t + 256]) * zsv[t + 256] * m;
    const _Float16 h0 = (_Float16)v0, h1 = (_Float16)v1;
    Zh[(size_t)row * NF + t] = h0;
    Zh[(size_t)row * NF + t + 256] = h1;
    v0 = (float)h0; v1 = (float)h1;
  } else {
    const int r = row - NROW;
    v0 = ip[(size_t)r * NF + t      ] * giv[t      ];
    v1 = ip[(size_t)r * NF + t + 256] * giv[t + 256];
    const _Float16 h0 = (_Float16)v0, h1 = (_Float16)v1;
    Zih[(size_t)r * NF + t] = h0;
    Zih[(size_t)r * NF + t + 256] = h1;
    v0 = (float)h0; v1 = (float)h1;
  }
  float nrm = v0 * v0 + v1 * v1;
  #pragma unroll
  for (int off = 32; off; off >>= 1) nrm += __shfl_xor(nrm, off);
  __shared__ float red[4];
  if ((t & 63) == 0) red[t >> 6] = nrm;
  __syncthreads();
  if (t == 0) {
    const float s = red[0] + red[1] + red[2] + red[3];
    if (row < NROW) rnorm[row] = s; else cnorm[row - NROW] = s;
  }
}

// ---------------------------------------------------------- MFMA GEMM ------
// S[M,N] = A[M,K] * B[N,K]^T, fp16 K-contiguous, fp32 accumulate.
// EPI 0: DKout = fp16(exp(-|rn_i + cn_j - 2S|) - CC)                [Kx gen]
// EPI 1: Cf = exp(-|rn_i + cn_j - 2S|) + 0.05*(i==j)  fp32          [Kreg]
// EPI 2: varacc_i += sum_j (S_ij + CC*u_j) * (CC + DK_ij)           [t o Kx]
// EPI 3: Cf = ((S_ij + CC*colsumR_j)*stdv_j + meanv_j) * mask_i     [x_new]
template <int EPI>
__global__ __launch_bounds__(256) void mfma_gemm(
    const _Float16* __restrict__ A, const _Float16* __restrict__ B,
    int M, int N, int K,
    const float* __restrict__ rn, const float* __restrict__ cn,
    _Float16* __restrict__ DKout, float* __restrict__ Cf,
    const _Float16* __restrict__ DK, const float* __restrict__ u,
    float* __restrict__ varacc,
    const float* __restrict__ colsumR,
    const float* __restrict__ stdv, const float* __restrict__ meanv,
    const int* __restrict__ mask)
{
  __shared__ __align__(16) _Float16 As[128 * 32];
  __shared__ __align__(16) _Float16 Bs[128 * 32];
  const int tid = threadIdx.x;
  const int w = tid >> 6, L = tid & 63;
  const int wm = w >> 1, wn = w & 1;
  const int bn = blockIdx.x, bm = blockIdx.y;
  const int lq = L >> 4;
  const int lr = L & 15;

  floatx4 acc[4][4] = {};

  const _Float16* Ag = A + (size_t)(bm * 128) * K;
  const _Float16* Bg = B + (size_t)(bn * 128) * K;
  const int srow = w * 32 + (L >> 2);
  const int scol = (L & 3) * 8;

  for (int k0 = 0; k0 < K; k0 += 32) {
    #pragma unroll
    for (int t = 0; t < 2; ++t) {
      const int r = srow + t * 16;
      gload16(Ag + (size_t)r * K + k0 + scol, As + r * 32 + scol);
      gload16(Bg + (size_t)r * K + k0 + scol, Bs + r * 32 + scol);
    }
    __syncthreads();
    half8 af[4], bf[4];
    #pragma unroll
    for (int mi = 0; mi < 4; ++mi)
      af[mi] = *(const half8*)&As[(wm * 64 + mi * 16 + lr) * 32 + lq * 8];
    #pragma unroll
    for (int ni = 0; ni < 4; ++ni)
      bf[ni] = *(const half8*)&Bs[(wn * 64 + ni * 16 + lr) * 32 + lq * 8];
    #pragma unroll
    for (int mi = 0; mi < 4; ++mi)
      #pragma unroll
      for (int ni = 0; ni < 4; ++ni)
        acc[mi][ni] = __builtin_amdgcn_mfma_f32_16x16x32_f16(
            af[mi], bf[ni], acc[mi][ni], 0, 0, 0);
    __syncthreads();
  }

  // C/D layout: col = lane&15, row = (lane>>4)*4 + reg
  const int grb = bm * 128 + wm * 64;
  const int gcb = bn * 128 + wn * 64;

  if constexpr (EPI == 2) {
    #pragma unroll
    for (int mi = 0; mi < 4; ++mi)
      #pragma unroll
      for (int e = 0; e < 4; ++e) {
        const int gr = grb + mi * 16 + lq * 4 + e;
        float partial = 0.f;
        #pragma unroll
        for (int ni = 0; ni < 4; ++ni) {
          const int gc = gcb + ni * 16 + lr;
          const float t = acc[mi][ni][e] + CC * u[gc];
          const float kx = CC + (float)DK[(size_t)gr * N + gc];
          partial += t * kx;
        }
        partial += __shfl_xor(partial, 1);
        partial += __shfl_xor(partial, 2);
        partial += __shfl_xor(partial, 4);
        partial += __shfl_xor(partial, 8);
        if (lr == 0) atomicAdd(&varacc[gr], partial);
      }
  } else if constexpr (EPI == 3) {
    #pragma unroll
    for (int mi = 0; mi < 4; ++mi)
      #pragma unroll
      for (int e = 0; e < 4; ++e) {
        const int gr = grb + mi * 16 + lq * 4 + e;
        const float mrow = (mask[gr] != 0) ? 1.f : 0.f;
        #pragma unroll
        for (int ni = 0; ni < 4; ++ni) {
          const int gc = gcb + ni * 16 + lr;
          const float v = acc[mi][ni][e] + CC * colsumR[gc];
          Cf[(size_t)gr * N + gc] = (v * stdv[gc] + meanv[gc]) * mrow;
        }
      }
  } else {
    #pragma unroll
    for (int mi = 0; mi < 4; ++mi)
      #pragma unroll
      for (int e = 0; e < 4; ++e) {
        const int gr = grb + mi * 16 + lq * 4 + e;
        const float rni = rn[gr];
        #pragma unroll
        for (int ni = 0; ni < 4; ++ni) {
          const int gc = gcb + ni * 16 + lr;
          const float d = rni + cn[gc] - 2.f * acc[mi][ni][e];
          float kx = expf(-fabsf(d));
          if constexpr (EPI == 0) {
            DKout[(size_t)gr * N + gc] = (_Float16)(kx - CC);
          } else {
            if (gr == gc) kx += 0.05f;
            Cf[(size_t)gr * N + gc] = kx;
          }
        }
      }
  }
}

// ------------------------------------------------------------ fp32 GEMM ----
// C[M,N] = A[M,K]*B[K,N], 64x64 tile (R = Kinv * P only)
__global__ __launch_bounds__(256) void gemm_f32(
    const float* __restrict__ A, const float* __restrict__ B,
    float* __restrict__ C, int M, int N, int K)
{
  constexpr int BM = 64, BN = 64, BK = 16;
  const int tid = threadIdx.x;
  const int tx = tid % 16, ty = tid / 16;
  const int bn = blockIdx.x, bm = blockIdx.y;
  __shared__ float As[BK][BM + 4];
  __shared__ float Bs[BK][BN + 4];
  float acc[4][4] = {};
  const float* Ag = A + (size_t)bm * BM * K;
  const float* Bg = B + bn * BN;
  for (int k0 = 0; k0 < K; k0 += BK) {
    {
      const int r = tid >> 2, c4 = (tid & 3) << 2;
      const float4 av = *(const float4*)(Ag + (size_t)r * K + k0 + c4);
      As[c4 + 0][r] = av.x; As[c4 + 1][r] = av.y;
      As[c4 + 2][r] = av.z; As[c4 + 3][r] = av.w;
      const int kr = tid / 16, nc = (tid % 16) << 2;
      *(float4*)&Bs[kr][nc] = *(const float4*)(Bg + (size_t)(k0 + kr) * N + nc);
    }
    __syncthreads();
    #pragma unroll
    for (int kk = 0; kk < BK; ++kk) {
      const float4 a4 = *(const float4*)&As[kk][ty * 4];
      const float4 b4 = *(const float4*)&Bs[kk][tx * 4];
      const float a[4] = {a4.x, a4.y, a4.z, a4.w};
      const float b[4] = {b4.x, b4.y, b4.z, b4.w};
      #pragma unroll
      for (int i = 0; i < 4; ++i)
        #pragma unroll
        for (int j = 0; j < 4; ++j) acc[i][j] += a[i] * b[j];
    }
    __syncthreads();
  }
  #pragma unroll
  for (int i = 0; i < 4; ++i) {
    float4 o4; o4.x = acc[i][0]; o4.y = acc[i][1]; o4.z = acc[i][2]; o4.w = acc[i][3];
    *(float4*)(C + (size_t)(bm * BM + ty * 4 + i) * N + bn * BN + tx * 4) = o4;
  }
}

// ------------------------------------------------- blocked Gauss-Jordan ----
// Single cooperative kernel. Per iter k (o=64k):
//   apply phase: row A_oj = P_k*Bsave_j; col A_io = -CP_i;
//                big A_ij -= CP_i*Bsave_j; tile (o+64,o+64) additionally runs
//                the 64-step pivot loop producing Pall[k+1].
//   prep phase:  CP_i = A[i][o']*P_{k+1};  Bsave = copy of row panel A[o'][:]
// 512 blocks (2/CU co-resident @ 34.8KB LDS), grid.sync() between phases.

__device__ __forceinline__ void pivot64(float* D, int t)  // D: 64x68 in LDS
{
  const int di = t >> 2, c0 = (t & 3) * 16;
  for (int s = 0; s < 64; ++s) {
    const float p = 1.0f / D[s * 68 + s];
    if (t < 64 && t != s) D[s * 68 + t] *= p;
    __syncthreads();
    if (di != s) {
      const float f = D[di * 68 + s];   // same-wave lockstep: reads precede writes
      #pragma unroll
      for (int c = c0; c < c0 + 16; c += 4) {
        float4 ds = *(const float4*)&D[s * 68 + c];
        float4 dv = *(const float4*)&D[di * 68 + c];
        dv.x -= f * ds.x; dv.y -= f * ds.y; dv.z -= f * ds.z; dv.w -= f * ds.w;
        *(float4*)&D[di * 68 + c] = dv;
      }
      if (s >= c0 && s < c0 + 16) D[di * 68 + s] = -f * p;   // fix garbage lane
    }
    if (t == 0) D[s * 68 + s] = p;
    __syncthreads();
  }
}

__device__ void apply_job(
    float* __restrict__ A, float* __restrict__ Pall,
    const float* __restrict__ CP, const float* __restrict__ Bsave,
    int k, int job, int t, float* S1, float* S2)
{
  if (job < 0) return;
  const int o = k * 64;
  const int i0 = (job >> 5) * 64, j0 = (job & 31) * 64;
  if (i0 == o && j0 == o) return;

  if (j0 == o) {                       // col: A_io = -CP_i
    #pragma unroll
    for (int l = 0; l < 4; ++l) {
      const int v = t + l * 256;
      const int r = v >> 4, c4 = (v & 15) << 2;
      float4 x = *(const float4*)(CP + (size_t)(i0 + r) * 64 + c4);
      x.x = -x.x; x.y = -x.y; x.z = -x.z; x.w = -x.w;
      *(float4*)(A + (size_t)(i0 + r) * MIND + o + c4) = x;
    }
    return;
  }

  __syncthreads();                     // previous job's LDS readers done
  const bool isrow = (i0 == o);
  const float* Lsrc = isrow ? (Pall + (size_t)k * 4096) : (CP + (size_t)i0 * 64);
  #pragma unroll
  for (int l = 0; l < 4; ++l) {
    const int v = t + l * 256;
    const int r = v >> 4, c4 = (v & 15) << 2;
    const float4 lv = *(const float4*)(Lsrc + r * 64 + c4);
    S1[(c4 + 0) * 68 + r] = lv.x; S1[(c4 + 1) * 68 + r] = lv.y;
    S1[(c4 + 2) * 68 + r] = lv.z; S1[(c4 + 3) * 68 + r] = lv.w;
    *(float4*)&S2[r * 68 + c4] = *(const float4*)(Bsave + (size_t)r * MIND + j0 + c4);
  }
  __syncthreads();
  const int ty = t >> 4, tx = t & 15;
  float acc[4][4] = {};
  for (int s = 0; s < 64; ++s) {
    const float4 a4 = *(const float4*)&S1[s * 68 + ty * 4];
    const float4 b4 = *(const float4*)&S2[s * 68 + tx * 4];
    const float a[4] = {a4.x, a4.y, a4.z, a4.w};
    const float b[4] = {b4.x, b4.y, b4.z, b4.w};
    #pragma unroll
    for (int i = 0; i < 4; ++i)
      #pragma unroll
      for (int j = 0; j < 4; ++j) acc[i][j] += a[i] * b[j];
  }

  if (isrow) {                         // A_oj = P * Bsave_j
    #pragma unroll
    for (int i = 0; i < 4; ++i) {
      float4 o4; o4.x = acc[i][0]; o4.y = acc[i][1]; o4.z = acc[i][2]; o4.w = acc[i][3];
      *(float4*)(A + (size_t)(o + ty * 4 + i) * MIND + j0 + tx * 4) = o4;
    }
    return;
  }

  const bool isdiag = (k < 31) && (i0 == o + 64) && (j0 == o + 64);
  if (!isdiag) {                       // big: A_ij -= CP_i * Bsave_j
    #pragma unroll
    for (int i = 0; i < 4; ++i) {
      float* cp = A + (size_t)(i0 + ty * 4 + i) * MIND + j0 + tx * 4;
      float4 cv = *(const float4*)cp;
      cv.x -= acc[i][0]; cv.y -= acc[i][1]; cv.z -= acc[i][2]; cv.w -= acc[i][3];
      *(float4*)cp = cv;
    }
    return;
  }

  // diag-next: D = A - acc in LDS, pivot, emit Pall[k+1] + A
  __syncthreads();                     // S1 GEMM readers done
  #pragma unroll
  for (int i = 0; i < 4; ++i) {
    const float4 cv = *(const float4*)(A + (size_t)(i0 + ty * 4 + i) * MIND + j0 + tx * 4);
    S1[(ty * 4 + i) * 68 + tx * 4 + 0] = cv.x - acc[i][0];
    S1[(ty * 4 + i) * 68 + tx * 4 + 1] = cv.y - acc[i][1];
    S1[(ty * 4 + i) * 68 + tx * 4 + 2] = cv.z - acc[i][2];
    S1[(ty * 4 + i) * 68 + tx * 4 + 3] = cv.w - acc[i][3];
  }
  __syncthreads();
  pivot64(S1, t);
  float* Pn = Pall + (size_t)(k + 1) * 4096;
  #pragma unroll
  for (int l = 0; l < 4; ++l) {
    const int v = t + l * 256;
    const int r = v >> 4, c4 = (v & 15) << 2;
    const float4 dv = *(const float4*)&S1[r * 68 + c4];
    *(float4*)(Pn + r * 64 + c4) = dv;
    *(float4*)(A + (size_t)(i0 + r) * MIND + j0 + c4) = dv;
  }
}

__device__ void prep_job(
    const float* __restrict__ A, const float* __restrict__ Pall,
    float* __restrict__ CP, float* __restrict__ Bsave,
    int k, int b, int t, float* S1, float* S2)
{
  const int o = k * 64;
  if (b >= 64) return;
  if (b >= 32) {                       // Bsave tile copy
    const int j0 = (b - 32) * 64;
    #pragma unroll
    for (int l = 0; l < 4; ++l) {
      const int v = t + l * 256;
      const int r = v >> 4, c4 = (v & 15) << 2;
      *(float4*)(Bsave + (size_t)r * MIND + j0 + c4) =
          *(const float4*)(A + (size_t)(o + r) * MIND + j0 + c4);
    }
    return;
  }
  const int i0 = b * 64;
  if (i0 == o) return;
  __syncthreads();                     // previous phase's LDS readers done
  const float* P = Pall + (size_t)k * 4096;
  #pragma unroll
  for (int l = 0; l < 4; ++l) {
    const int v = t + l * 256;
    const int r = v >> 4, c4 = (v & 15) << 2;
    const float4 av = *(const float4*)(A + (size_t)(i0 + r) * MIND + o + c4);
    S1[(c4 + 0) * 68 + r] = av.x; S1[(c4 + 1) * 68 + r] = av.y;
    S1[(c4 + 2) * 68 + r] = av.z; S1[(c4 + 3) * 68 + r] = av.w;
    *(float4*)&S2[r * 68 + c4] = *(const float4*)(P + r * 64 + c4);
  }
  __syncthreads();
  const int ty = t >> 4, tx = t & 15;
  float acc[4][4] = {};
  for (int s = 0; s < 64; ++s) {
    const float4 a4 = *(const float4*)&S1[s * 68 + ty * 4];
    const float4 b4 = *(const float4*)&S2[s * 68 + tx * 4];
    const float a[4] = {a4.x, a4.y, a4.z, a4.w};
    const float b[4] = {b4.x, b4.y, b4.z, b4.w};
    #pragma unroll
    for (int i = 0; i < 4; ++i)
      #pragma unroll
      for (int j = 0; j < 4; ++j) acc[i][j] += a[i] * b[j];
  }
  #pragma unroll
  for (int i = 0; i < 4; ++i) {
    float4 o4; o4.x = acc[i][0]; o4.y = acc[i][1]; o4.z = acc[i][2]; o4.w = acc[i][3];
    *(float4*)(CP + (size_t)(i0 + ty * 4 + i) * 64 + tx * 4) = o4;
  }
}

__global__ __launch_bounds__(256) void gj_coop(
    float* __restrict__ A, float* __restrict__ Pall,
    float* __restrict__ CP, float* __restrict__ Bsave)
{
  cg::grid_group grid = cg::this_grid();
  const int b = blockIdx.x;
  const int t = threadIdx.x;
  __shared__ float S1[64 * 68];
  __shared__ float S2[64 * 68];

  // bootstrap: Pall[0] = pivot(A_00), A_00 = P0
  if (b == 0) {
    #pragma unroll
    for (int l = 0; l < 4; ++l) {
      const int v = t + l * 256;
      const int r = v >> 4, c4 = (v & 15) << 2;
      *(float4*)&S1[r * 68 + c4] = *(const float4*)(A + (size_t)r * MIND + c4);
    }
    __syncthreads();
    pivot64(S1, t);
    #pragma unroll
    for (int l = 0; l < 4; ++l) {
      const int v = t + l * 256;
      const int r = v >> 4, c4 = (v & 15) << 2;
      const float4 dv = *(const float4*)&S1[r * 68 + c4];
      *(float4*)(Pall + r * 64 + c4) = dv;
      *(float4*)(A + (size_t)r * MIND + c4) = dv;
    }
  }
  grid.sync();
  prep_job(A, Pall, CP, Bsave, 0, b, t, S1, S2);
  grid.sync();

  for (int k = 0; k < 32; ++k) {
    int j1 = b, j2 = b + 512, j3 = -1;
    if (k < 31) {
      const int djob = 33 * (k + 1);   // tile (o+64, o+64)
      const int db = djob & 511;       // its owner block
      const int sib = djob ^ 512;      // owner's other job -> reassigned
      if (b == db) { j1 = djob; j2 = -1; }
      else if (b == ((db + 1) & 511)) { j3 = sib; }
    }
    apply_job(A, Pall, CP, Bsave, k, j1, t, S1, S2);
    apply_job(A, Pall, CP, Bsave, k, j2, t, S1, S2);
    apply_job(A, Pall, CP, Bsave, k, j3, t, S1, S2);
    grid.sync();
    if (k < 31) {
      prep_job(A, Pall, CP, Bsave, k + 1, b, t, S1, S2);
      grid.sync();
    }
  }
}

// ----------------------------------------------------------- helpers -------
__global__ __launch_bounds__(256) void rowsum_kernel(
    const float* __restrict__ Ai, float* __restrict__ u)
{
  const int row = blockIdx.x * 4 + (threadIdx.x >> 6);
  const int lane = threadIdx.x & 63;
  float s = 0.f;
  for (int c = lane; c < MIND; c += 64) s += Ai[(size_t)row * MIND + c];
  #pragma unroll
  for (int off = 32; off; off >>= 1) s += __shfl_xor(s, off);
  if (lane == 0) u[row] = s;
}

typedef _Float16 half4v __attribute__((ext_vector_type(4)));
__global__ __launch_bounds__(256) void cast_half4(
    const float* __restrict__ s, _Float16* __restrict__ d)
{
  const int i = (blockIdx.x * 256 + threadIdx.x) * 4;
  const float4 v = *(const float4*)(s + i);
  half4v h; h.x = (_Float16)v.x; h.y = (_Float16)v.y;
  h.z = (_Float16)v.z; h.w = (_Float16)v.w;
  *(half4v*)(d + i) = h;
}

// Rt[512,2048] = fp16(R[2048,512]^T)
__global__ __launch_bounds__(256) void transpose_cast(
    const float* __restrict__ R, _Float16* __restrict__ Rt)
{
  __shared__ float T[64][65];
  const int j0 = blockIdx.x * 64;
  const int f0 = blockIdx.y * 64;
  const int t = threadIdx.x;
  #pragma unroll
  for (int l = 0; l < 16; ++l) {
    const int idx = t + l * 256;
    T[idx >> 6][idx & 63] = R[(size_t)(j0 + (idx >> 6)) * NF + f0 + (idx & 63)];
  }
  __syncthreads();
  #pragma unroll
  for (int l = 0; l < 16; ++l) {
    const int idx = t + l * 256;
    const int fr = idx >> 6, jc = idx & 63;
    Rt[(size_t)(f0 + fr) * MIND + j0 + jc] = (_Float16)T[jc][fr];
  }
}

__global__ __launch_bounds__(256) void colsum_kernel(
    const float* __restrict__ R, float* __restrict__ cs)
{
  const int b = blockIdx.x;
  const int t = threadIdx.x;
  float s0 = 0.f, s1 = 0.f;
  for (int r = 0; r < 64; ++r) {
    s0 += R[(size_t)(b * 64 + r) * NF + t];
    s1 += R[(size_t)(b * 64 + r) * NF + t + 256];
  }
  atomicAdd(&cs[t], s0); atomicAdd(&cs[t + 256], s1);
}

__global__ __launch_bounds__(256) void var_finalize(
    const float* __restrict__ varacc, const int* __restrict__ mask,
    float* __restrict__ outv)
{
  const int i = blockIdx.x * 256 + threadIdx.x;
  const float m = (mask[i] != 0) ? 1.f : 0.f;
  outv[i] = (1.0f - varacc[i]) * m;
}

}  // namespace

extern "C" void kernel_launch(void* const* d_in, const int* in_sizes, int n_in,
                              void* d_out, int out_size, void* d_ws, size_t ws_size,
                              hipStream_t stream)
{
  (void)in_sizes; (void)n_in; (void)out_size; (void)ws_size;
  const float* x     = (const float*)d_in[0];
  const int*   mask  = (const int*)d_in[1];
  const float* ip    = (const float*)d_in[2];
  const float* gamma = (const float*)d_in[3];
  float* out = (float*)d_out;

  float* w       = (float*)d_ws;
  float* sum     = w;                     // 512
  float* sumsq   = w + 512;               // 512
  float* cnt     = w + 1024;              // 1 (padded 512)
  float* varacc  = w + 1536;              // 16384
  float* colsumR = w + 17920;             // 512   -> [0, 18432) zeroed
  float* meanv   = w + 18432;
  float* stdv    = w + 18944;
  float* zsv     = w + 19456;
  float* giv     = w + 19968;
  float* rnorm   = w + 20480;             // 16384
  float* cnorm   = w + 36864;             // 2048
  float* u       = w + 38912;             // 2048
  float* Ai      = w + 40960;             // 2048*2048 (Kreg -> Kinv in place)
  float* R       = w + 4235264;           // 2048*512
  float* Pall    = w + 5283840;           // 32*4096 pivot inverses
  float* CP      = w + 5414912;           // 2048*64
  float* Bsave   = w + 5545984;           // 64*2048
  _Float16* hb   = (_Float16*)(w + 5677056);
  _Float16* Zh   = hb;                    // 16384*512
  _Float16* Zih  = hb + 8388608;          // 2048*512
  _Float16* DK   = hb + 9437184;          // 16384*2048
  _Float16* Kih  = hb + 42991616;         // 2048*2048
  _Float16* Rt   = hb + 47185920;         // 512*2048

  hipMemsetAsync(w, 0, 18432 * sizeof(float), stream);

  stats_kernel<<<256, 256, 0, stream>>>(x, mask, sum, sumsq, cnt);
  finalize_stats<<<2, 256, 0, stream>>>(sum, sumsq, cnt, gamma, meanv, stdv, zsv, giv);
  make_z<<<NROW + MIND, 256, 0, stream>>>(x, mask, ip, meanv, zsv, giv, Zh, Zih, rnorm, cnorm);

  // DK = fp16(exp(-|rn+cn-2 Z Zi^T|) - CC)     [16384 x 2048]
  mfma_gemm<0><<<dim3(MIND / 128, NROW / 128), 256, 0, stream>>>(
      Zh, Zih, NROW, MIND, NF, rnorm, cnorm,
      DK, nullptr, nullptr, nullptr, nullptr, nullptr, nullptr, nullptr, nullptr);
  // Kreg fp32 = exp(-|...|) + 0.05 I           [2048 x 2048]
  mfma_gemm<1><<<dim3(MIND / 128, MIND / 128), 256, 0, stream>>>(
      Zih, Zih, MIND, MIND, NF, cnorm, cnorm,
      nullptr, Ai, nullptr, nullptr, nullptr, nullptr, nullptr, nullptr, nullptr);

  // blocked Gauss-Jordan inverse: one cooperative kernel
  {
    void* args[] = {(void*)&Ai, (void*)&Pall, (void*)&CP, (void*)&Bsave};
    hipLaunchCooperativeKernel((void*)gj_coop, dim3(512), dim3(256), args, 0, stream);
  }

  // R = Kinv * P (fp32), then Rt = fp16(R^T), colsumR, u = rowsum(Kinv), Kih
  gemm_f32<<<dim3(NF / 64, MIND / 64), 256, 0, stream>>>(Ai, ip, R, MIND, NF, MIND);
  transpose_cast<<<dim3(MIND / 64, NF / 64), 256, 0, stream>>>(R, Rt);
  colsum_kernel<<<MIND / 64, 256, 0, stream>>>(R, colsumR);
  rowsum_kernel<<<MIND / 4, 256, 0, stream>>>(Ai, u);
  cast_half4<<<(MIND * MIND) / 1024, 256, 0, stream>>>(Ai, Kih);

  // varacc_i = sum_j (DK Kinv + CC*1 u^T)_ij * (CC + DK_ij)
  mfma_gemm<2><<<dim3(MIND / 128, NROW / 128), 256, 0, stream>>>(
      DK, Kih, NROW, MIND, MIND, nullptr, nullptr,
      nullptr, nullptr, DK, u, varacc, nullptr, nullptr, nullptr, nullptr);

  // x_new = ((DK Rt^T + CC*colsumR)*std + mean) * mask
  mfma_gemm<3><<<dim3(NF / 128, NROW / 128), 256, 0, stream>>>(
      DK, Rt, NROW, NF, MIND, nullptr, nullptr,
      nullptr, out, nullptr, nullptr, nullptr, colsumR, stdv, meanv, mask);

  var_finalize<<<NROW / 256, 256, 0, stream>>>(varacc, mask, out + (size_t)NROW * NF);
}

// Round 7
// 2202.857 us; speedup vs baseline: 2.3326x; 2.3326x over previous
//
#include <hip/hip_runtime.h>
#include <math.h>
#include <stdint.h>

namespace {

constexpr int NROW = 16384;   // B*A
constexpr int NF   = 512;     // n_in
constexpr int MIND = 2048;    // inducing points
constexpr float CC = 0.98f;   // centering constant: Kx = exp(-d), d ~ 0.004

typedef _Float16 half8 __attribute__((ext_vector_type(8)));
typedef float floatx4 __attribute__((ext_vector_type(4)));

__device__ __forceinline__ void gload16(const void* g, void* l) {
  __builtin_amdgcn_global_load_lds(
      (__attribute__((address_space(1))) void*)g,
      (__attribute__((address_space(3))) void*)l, 16, 0, 0);
}

// ---------------------------------------------------------------- stats ----
__global__ __launch_bounds__(256) void stats_kernel(
    const float* __restrict__ x, const int* __restrict__ mask,
    float* __restrict__ sum, float* __restrict__ sumsq, float* __restrict__ cnt)
{
  const int t = threadIdx.x;
  const int row0 = blockIdx.x * 64;
  float s0 = 0.f, s1 = 0.f, q0 = 0.f, q1 = 0.f, c = 0.f;
  for (int r = 0; r < 64; ++r) {
    const int row = row0 + r;
    const float m = (mask[row] != 0) ? 1.f : 0.f;
    const float v0 = x[(size_t)row * NF + t];
    const float v1 = x[(size_t)row * NF + t + 256];
    s0 += m * v0; q0 += m * v0 * v0;
    s1 += m * v1; q1 += m * v1 * v1;
    c += m;
  }
  atomicAdd(&sum[t], s0);        atomicAdd(&sum[t + 256], s1);
  atomicAdd(&sumsq[t], q0);      atomicAdd(&sumsq[t + 256], q1);
  if (t == 0) atomicAdd(cnt, c);
}

__global__ __launch_bounds__(256) void finalize_stats(
    const float* __restrict__ sum, const float* __restrict__ sumsq,
    const float* __restrict__ cnt, const float* __restrict__ gamma,
    float* __restrict__ meanv, float* __restrict__ stdv,
    float* __restrict__ zsv, float* __restrict__ giv)
{
  const int f = blockIdx.x * 256 + threadIdx.x;   // <<<2,256>>>
  const float n = cnt[0];
  const float mu = sum[f] / n;
  const float var = (sumsq[f] - sum[f] * mu) / (n - 1.0f);
  const float sd = sqrtf(var) + 1e-5f;
  const float g = gamma[f];
  const float g2 = g * g + 0.001f;
  meanv[f] = mu;
  stdv[f]  = sd;
  zsv[f]   = 1.0f / (sd * g2);
  giv[f]   = 1.0f / g2;
}

// z rows (masked, normalized, /g2) fp16 + zi rows fp16 + fp32 norms of the
// fp16-ROUNDED values (so d_jj ~ 0 exactly)
__global__ __launch_bounds__(256) void make_z(
    const float* __restrict__ x, const int* __restrict__ mask,
    const float* __restrict__ ip, const float* __restrict__ meanv,
    const float* __restrict__ zsv, const float* __restrict__ giv,
    _Float16* __restrict__ Zh, _Float16* __restrict__ Zih,
    float* __restrict__ rnorm, float* __restrict__ cnorm)
{
  const int row = blockIdx.x;
  const int t = threadIdx.x;
  float v0, v1;
  if (row < NROW) {
    const float m = (mask[row] != 0) ? 1.f : 0.f;
    v0 = (x[(size_t)row * NF + t      ] - meanv[t      ]) * zsv[t      ] * m;
    v1 = (x[(size_t)row * NF + t + 256] - meanv[t + 256]) * zsv[t + 256] * m;
    const _Float16 h0 = (_Float16)v0, h1 = (_Float16)v1;
    Zh[(size_t)row * NF + t] = h0;
    Zh[(size_t)row * NF + t + 256] = h1;
    v0 = (float)h0; v1 = (float)h1;
  } else {
    const int r = row - NROW;
    v0 = ip[(size_t)r * NF + t      ] * giv[t      ];
    v1 = ip[(size_t)r * NF + t + 256] * giv[t + 256];
    const _Float16 h0 = (_Float16)v0, h1 = (_Float16)v1;
    Zih[(size_t)r * NF + t] = h0;
    Zih[(size_t)r * NF + t + 256] = h1;
    v0 = (float)h0; v1 = (float)h1;
  }
  float nrm = v0 * v0 + v1 * v1;
  #pragma unroll
  for (int off = 32; off; off >>= 1) nrm += __shfl_xor(nrm, off);
  __shared__ float red[4];
  if ((t & 63) == 0) red[t >> 6] = nrm;
  __syncthreads();
  if (t == 0) {
    const float s = red[0] + red[1] + red[2] + red[3];
    if (row < NROW) rnorm[row] = s; else cnorm[row - NROW] = s;
  }
}

// ---------------------------------------------------------- MFMA GEMM ------
// S[M,N] = A[M,K] * B[N,K]^T, fp16 K-contiguous, fp32 accumulate.
// EPI 0: DKout = fp16(exp(-|rn_i + cn_j - 2S|) - CC)                [Kx gen]
// EPI 1: Cf = exp(-|rn_i + cn_j - 2S|) + 0.05*(i==j)  fp32          [Kreg]
// EPI 2: varacc_i += sum_j (S_ij + CC*u_j) * (CC + DK_ij)           [t o Kx]
// EPI 3: Cf = ((S_ij + CC*colsumR_j)*stdv_j + meanv_j) * mask_i     [x_new]
template <int EPI>
__global__ __launch_bounds__(256) void mfma_gemm(
    const _Float16* __restrict__ A, const _Float16* __restrict__ B,
    int M, int N, int K,
    const float* __restrict__ rn, const float* __restrict__ cn,
    _Float16* __restrict__ DKout, float* __restrict__ Cf,
    const _Float16* __restrict__ DK, const float* __restrict__ u,
    float* __restrict__ varacc,
    const float* __restrict__ colsumR,
    const float* __restrict__ stdv, const float* __restrict__ meanv,
    const int* __restrict__ mask)
{
  __shared__ __align__(16) _Float16 As[128 * 32];
  __shared__ __align__(16) _Float16 Bs[128 * 32];
  const int tid = threadIdx.x;
  const int w = tid >> 6, L = tid & 63;
  const int wm = w >> 1, wn = w & 1;
  const int bn = blockIdx.x, bm = blockIdx.y;
  const int lq = L >> 4;
  const int lr = L & 15;

  floatx4 acc[4][4] = {};

  const _Float16* Ag = A + (size_t)(bm * 128) * K;
  const _Float16* Bg = B + (size_t)(bn * 128) * K;
  const int srow = w * 32 + (L >> 2);
  const int scol = (L & 3) * 8;

  for (int k0 = 0; k0 < K; k0 += 32) {
    #pragma unroll
    for (int t = 0; t < 2; ++t) {
      const int r = srow + t * 16;
      gload16(Ag + (size_t)r * K + k0 + scol, As + r * 32 + scol);
      gload16(Bg + (size_t)r * K + k0 + scol, Bs + r * 32 + scol);
    }
    __syncthreads();
    half8 af[4], bf[4];
    #pragma unroll
    for (int mi = 0; mi < 4; ++mi)
      af[mi] = *(const half8*)&As[(wm * 64 + mi * 16 + lr) * 32 + lq * 8];
    #pragma unroll
    for (int ni = 0; ni < 4; ++ni)
      bf[ni] = *(const half8*)&Bs[(wn * 64 + ni * 16 + lr) * 32 + lq * 8];
    #pragma unroll
    for (int mi = 0; mi < 4; ++mi)
      #pragma unroll
      for (int ni = 0; ni < 4; ++ni)
        acc[mi][ni] = __builtin_amdgcn_mfma_f32_16x16x32_f16(
            af[mi], bf[ni], acc[mi][ni], 0, 0, 0);
    __syncthreads();
  }

  // C/D layout: col = lane&15, row = (lane>>4)*4 + reg
  const int grb = bm * 128 + wm * 64;
  const int gcb = bn * 128 + wn * 64;

  if constexpr (EPI == 2) {
    #pragma unroll
    for (int mi = 0; mi < 4; ++mi)
      #pragma unroll
      for (int e = 0; e < 4; ++e) {
        const int gr = grb + mi * 16 + lq * 4 + e;
        float partial = 0.f;
        #pragma unroll
        for (int ni = 0; ni < 4; ++ni) {
          const int gc = gcb + ni * 16 + lr;
          const float t = acc[mi][ni][e] + CC * u[gc];
          const float kx = CC + (float)DK[(size_t)gr * N + gc];
          partial += t * kx;
        }
        partial += __shfl_xor(partial, 1);
        partial += __shfl_xor(partial, 2);
        partial += __shfl_xor(partial, 4);
        partial += __shfl_xor(partial, 8);
        if (lr == 0) atomicAdd(&varacc[gr], partial);
      }
  } else if constexpr (EPI == 3) {
    #pragma unroll
    for (int mi = 0; mi < 4; ++mi)
      #pragma unroll
      for (int e = 0; e < 4; ++e) {
        const int gr = grb + mi * 16 + lq * 4 + e;
        const float mrow = (mask[gr] != 0) ? 1.f : 0.f;
        #pragma unroll
        for (int ni = 0; ni < 4; ++ni) {
          const int gc = gcb + ni * 16 + lr;
          const float v = acc[mi][ni][e] + CC * colsumR[gc];
          Cf[(size_t)gr * N + gc] = (v * stdv[gc] + meanv[gc]) * mrow;
        }
      }
  } else {
    #pragma unroll
    for (int mi = 0; mi < 4; ++mi)
      #pragma unroll
      for (int e = 0; e < 4; ++e) {
        const int gr = grb + mi * 16 + lq * 4 + e;
        const float rni = rn[gr];
        #pragma unroll
        for (int ni = 0; ni < 4; ++ni) {
          const int gc = gcb + ni * 16 + lr;
          const float d = rni + cn[gc] - 2.f * acc[mi][ni][e];
          float kx = expf(-fabsf(d));
          if constexpr (EPI == 0) {
            DKout[(size_t)gr * N + gc] = (_Float16)(kx - CC);
          } else {
            if (gr == gc) kx += 0.05f;
            Cf[(size_t)gr * N + gc] = kx;
          }
        }
      }
  }
}

// ------------------------------------------------------------ fp32 GEMM ----
// C[M,N] = A[M,K]*B[K,N], 64x64 tile (R = Kinv * P only)
__global__ __launch_bounds__(256) void gemm_f32(
    const float* __restrict__ A, const float* __restrict__ B,
    float* __restrict__ C, int M, int N, int K)
{
  constexpr int BM = 64, BN = 64, BK = 16;
  const int tid = threadIdx.x;
  const int tx = tid % 16, ty = tid / 16;
  const int bn = blockIdx.x, bm = blockIdx.y;
  __shared__ float As[BK][BM + 4];
  __shared__ float Bs[BK][BN + 4];
  float acc[4][4] = {};
  const float* Ag = A + (size_t)bm * BM * K;
  const float* Bg = B + bn * BN;
  for (int k0 = 0; k0 < K; k0 += BK) {
    {
      const int r = tid >> 2, c4 = (tid & 3) << 2;
      const float4 av = *(const float4*)(Ag + (size_t)r * K + k0 + c4);
      As[c4 + 0][r] = av.x; As[c4 + 1][r] = av.y;
      As[c4 + 2][r] = av.z; As[c4 + 3][r] = av.w;
      const int kr = tid / 16, nc = (tid % 16) << 2;
      *(float4*)&Bs[kr][nc] = *(const float4*)(Bg + (size_t)(k0 + kr) * N + nc);
    }
    __syncthreads();
    #pragma unroll
    for (int kk = 0; kk < BK; ++kk) {
      const float4 a4 = *(const float4*)&As[kk][ty * 4];
      const float4 b4 = *(const float4*)&Bs[kk][tx * 4];
      const float a[4] = {a4.x, a4.y, a4.z, a4.w};
      const float b[4] = {b4.x, b4.y, b4.z, b4.w};
      #pragma unroll
      for (int i = 0; i < 4; ++i)
        #pragma unroll
        for (int j = 0; j < 4; ++j) acc[i][j] += a[i] * b[j];
    }
    __syncthreads();
  }
  #pragma unroll
  for (int i = 0; i < 4; ++i) {
    float4 o4; o4.x = acc[i][0]; o4.y = acc[i][1]; o4.z = acc[i][2]; o4.w = acc[i][3];
    *(float4*)(C + (size_t)(bm * BM + ty * 4 + i) * N + bn * BN + tx * 4) = o4;
  }
}

// ------------------------------------------------- blocked Gauss-Jordan ----
// One launch PER ITERATION, zero intra-launch cross-block deps.
// Launch k inputs (written by launch k-1 / boot): Pall[k], Cs_cur, Bs_cur.
// Launch k outputs: A updated; Cs_nxt/Bs_nxt panel copies; Pall[k+1] (pivot
// fused into the (k+1,k+1) tile's block).
// Each block owns tiles (bi,bj0) and (bi,bj0+16): CP_i = Cs_i*P_k computed
// ONCE per block and reused for both tiles (col tile is just -CP_i).

__device__ __forceinline__ void pivot64(float* D, int t)  // D: 64x68 in LDS
{
  const int i = t >> 2, c0 = (t & 3) * 16;
  for (int s = 0; s < 64; ++s) {
    const float p = 1.0f / D[s * 68 + s];
    if (t < 64 && t != s) D[s * 68 + t] *= p;
    __syncthreads();
    if (i != s) {
      const float f = D[i * 68 + s];   // 4 threads/row, same wave: lockstep
      #pragma unroll
      for (int c = c0; c < c0 + 16; c += 4) {
        float4 ds = *(const float4*)&D[s * 68 + c];
        float4 dv = *(const float4*)&D[i * 68 + c];
        dv.x -= f * ds.x; dv.y -= f * ds.y; dv.z -= f * ds.z; dv.w -= f * ds.w;
        *(float4*)&D[i * 68 + c] = dv;
      }
      if (s >= c0 && s < c0 + 16) D[i * 68 + s] = -f * p;
    }
    if (t == 0) D[s * 68 + s] = p;
    __syncthreads();
  }
}

__device__ __forceinline__ void stage_N(float* S, const float* g, int ldg, int t) {
  #pragma unroll
  for (int l = 0; l < 4; ++l) {
    const int v = t + l * 256, r = v >> 4, c4 = (v & 15) << 2;
    *(float4*)&S[r * 68 + c4] = *(const float4*)(g + (size_t)r * ldg + c4);
  }
}

__device__ __forceinline__ void stage_T(float* S, const float* g, int ldg, int t) {
  #pragma unroll
  for (int l = 0; l < 4; ++l) {
    const int v = t + l * 256, r = v >> 4, c4 = (v & 15) << 2;
    const float4 gv = *(const float4*)(g + (size_t)r * ldg + c4);
    S[(c4 + 0) * 68 + r] = gv.x; S[(c4 + 1) * 68 + r] = gv.y;
    S[(c4 + 2) * 68 + r] = gv.z; S[(c4 + 3) * 68 + r] = gv.w;
  }
}

__device__ __forceinline__ void mac64(const float* S1, const float* S2,
                                      float (&o)[4][4], int ty, int tx) {
  for (int s = 0; s < 64; ++s) {
    const float4 av = *(const float4*)&S1[s * 68 + ty * 4];
    const float4 bv = *(const float4*)&S2[s * 68 + tx * 4];
    const float aa[4] = {av.x, av.y, av.z, av.w};
    const float bb[4] = {bv.x, bv.y, bv.z, bv.w};
    #pragma unroll
    for (int r = 0; r < 4; ++r)
      #pragma unroll
      for (int c = 0; c < 4; ++c) o[r][c] += aa[r] * bb[c];
  }
}

// boot: P[0] = pivot(A_00); Cs0 = A[:, 0:64]; Bs0 = A[0:64, :]
__global__ __launch_bounds__(256) void gj_boot(
    const float* __restrict__ A, float* __restrict__ Pall,
    float* __restrict__ Cs0, float* __restrict__ Bs0)
{
  const int b = blockIdx.x;   // 64 blocks
  const int t = threadIdx.x;
  if (b < 32) {
    #pragma unroll
    for (int l = 0; l < 4; ++l) {
      const int v = t + l * 256, r = v >> 4, c4 = (v & 15) << 2;
      *(float4*)(Cs0 + (size_t)(b * 64 + r) * 64 + c4) =
          *(const float4*)(A + (size_t)(b * 64 + r) * MIND + c4);
    }
  } else {
    const int j0 = (b - 32) * 64;
    #pragma unroll
    for (int l = 0; l < 4; ++l) {
      const int v = t + l * 256, r = v >> 4, c4 = (v & 15) << 2;
      *(float4*)(Bs0 + (size_t)r * MIND + j0 + c4) =
          *(const float4*)(A + (size_t)r * MIND + j0 + c4);
    }
  }
  if (b == 0) {
    __shared__ float S1[64 * 68];
    #pragma unroll
    for (int l = 0; l < 4; ++l) {
      const int v = t + l * 256, r = v >> 4, c4 = (v & 15) << 2;
      *(float4*)&S1[r * 68 + c4] = *(const float4*)(A + (size_t)r * MIND + c4);
    }
    __syncthreads();
    pivot64(S1, t);
    #pragma unroll
    for (int l = 0; l < 4; ++l) {
      const int v = t + l * 256, r = v >> 4, c4 = (v & 15) << 2;
      *(float4*)(Pall + r * 64 + c4) = *(const float4*)&S1[r * 68 + c4];
    }
  }
}

__global__ __launch_bounds__(256) void gj_step(
    float* __restrict__ A, float* __restrict__ Pall,
    const float* __restrict__ Cs_cur, const float* __restrict__ Bs_cur,
    float* __restrict__ Cs_nxt, float* __restrict__ Bs_nxt, int k)
{
  __shared__ float S1[64 * 68];
  __shared__ float S2[64 * 68];
  const int t = threadIdx.x;
  const int ty = t >> 4, tx = t & 15;
  const int bi = blockIdx.x >> 4;
  const int bj0 = blockIdx.x & 15;
  const int js[2] = {bj0, bj0 + 16};
  const float* Pk = Pall + (size_t)k * 4096;

  float nv[2][4][4];

  if (bi == k) {
    // -------- row-panel block: S1 = Pk^T staged once, serves both tiles
    stage_T(S1, Pk, 64, t);
    #pragma unroll
    for (int q = 0; q < 2; ++q) {
      const int j = js[q];
      if (j == k) {                            // diag: A_kk = P_k
        #pragma unroll
        for (int r = 0; r < 4; ++r) {
          const float4 v = *(const float4*)(Pk + (ty * 4 + r) * 64 + tx * 4);
          nv[q][r][0] = v.x; nv[q][r][1] = v.y;
          nv[q][r][2] = v.z; nv[q][r][3] = v.w;
        }
      } else {                                 // row: P_k * Bs_j
        __syncthreads();
        stage_N(S2, Bs_cur + (size_t)j * 64, MIND, t);
        __syncthreads();
        float o[4][4] = {};
        mac64(S1, S2, o, ty, tx);
        #pragma unroll
        for (int r = 0; r < 4; ++r)
          #pragma unroll
          for (int c = 0; c < 4; ++c) nv[q][r][c] = o[r][c];
      }
    }
  } else {
    // -------- CP block: cp = Cs_i * P_k once, reused
    stage_T(S1, Cs_cur + (size_t)bi * 4096, 64, t);
    stage_N(S2, Pk, 64, t);
    __syncthreads();
    float cp[4][4] = {};
    mac64(S1, S2, cp, ty, tx);
    __syncthreads();                           // all done reading S1/S2
    #pragma unroll
    for (int r = 0; r < 4; ++r)
      #pragma unroll
      for (int c = 0; c < 4; ++c)
        S1[(tx * 4 + c) * 68 + ty * 4 + r] = cp[r][c];   // S1 = CP^T
    #pragma unroll
    for (int q = 0; q < 2; ++q) {
      const int j = js[q];
      if (j == k) {                            // col: A_ik = -CP_i
        #pragma unroll
        for (int r = 0; r < 4; ++r)
          #pragma unroll
          for (int c = 0; c < 4; ++c) nv[q][r][c] = -cp[r][c];
      } else {                                 // big: A_ij -= CP_i * Bs_j
        __syncthreads();
        stage_N(S2, Bs_cur + (size_t)j * 64, MIND, t);
        __syncthreads();
        float o[4][4] = {};
        mac64(S1, S2, o, ty, tx);
        #pragma unroll
        for (int r = 0; r < 4; ++r) {
          const float4 av = *(const float4*)(
              A + (size_t)(bi * 64 + ty * 4 + r) * MIND + j * 64 + tx * 4);
          nv[q][r][0] = av.x - o[r][0]; nv[q][r][1] = av.y - o[r][1];
          nv[q][r][2] = av.z - o[r][2]; nv[q][r][3] = av.w - o[r][3];
        }
      }
    }
  }

  // -------- epilogue: write A + panel copies for next launch
  #pragma unroll
  for (int q = 0; q < 2; ++q) {
    const int j = js[q];
    #pragma unroll
    for (int r = 0; r < 4; ++r) {
      float4 o4;
      o4.x = nv[q][r][0]; o4.y = nv[q][r][1];
      o4.z = nv[q][r][2]; o4.w = nv[q][r][3];
      *(float4*)(A + (size_t)(bi * 64 + ty * 4 + r) * MIND + j * 64 + tx * 4) = o4;
      if (k < 31 && j == k + 1)
        *(float4*)(Cs_nxt + (size_t)(bi * 64 + ty * 4 + r) * 64 + tx * 4) = o4;
      if (k < 31 && bi == k + 1)
        *(float4*)(Bs_nxt + (size_t)(ty * 4 + r) * MIND + j * 64 + tx * 4) = o4;
    }
  }

  // -------- fused pivot for next iteration
  if (k < 31 && bi == k + 1) {
    int q = -1;
    if (k + 1 < 16) { if (bj0 == k + 1) q = 0; }
    else            { if (bj0 == k + 1 - 16) q = 1; }
    if (q >= 0) {
      __syncthreads();
      #pragma unroll
      for (int r = 0; r < 4; ++r) {
        float4 o4;
        o4.x = nv[q][r][0]; o4.y = nv[q][r][1];
        o4.z = nv[q][r][2]; o4.w = nv[q][r][3];
        *(float4*)&S1[(ty * 4 + r) * 68 + tx * 4] = o4;
      }
      __syncthreads();
      pivot64(S1, t);
      float* Pn = Pall + (size_t)(k + 1) * 4096;
      #pragma unroll
      for (int l = 0; l < 4; ++l) {
        const int v = t + l * 256, r = v >> 4, c4 = (v & 15) << 2;
        *(float4*)(Pn + r * 64 + c4) = *(const float4*)&S1[r * 68 + c4];
      }
    }
  }
}

// ----------------------------------------------------------- helpers -------
__global__ __launch_bounds__(256) void rowsum_kernel(
    const float* __restrict__ Ai, float* __restrict__ u)
{
  const int row = blockIdx.x * 4 + (threadIdx.x >> 6);
  const int lane = threadIdx.x & 63;
  float s = 0.f;
  for (int c = lane; c < MIND; c += 64) s += Ai[(size_t)row * MIND + c];
  #pragma unroll
  for (int off = 32; off; off >>= 1) s += __shfl_xor(s, off);
  if (lane == 0) u[row] = s;
}

typedef _Float16 half4v __attribute__((ext_vector_type(4)));
__global__ __launch_bounds__(256) void cast_half4(
    const float* __restrict__ s, _Float16* __restrict__ d)
{
  const int i = (blockIdx.x * 256 + threadIdx.x) * 4;
  const float4 v = *(const float4*)(s + i);
  half4v h; h.x = (_Float16)v.x; h.y = (_Float16)v.y;
  h.z = (_Float16)v.z; h.w = (_Float16)v.w;
  *(half4v*)(d + i) = h;
}

// Rt[512,2048] = fp16(R[2048,512]^T)
__global__ __launch_bounds__(256) void transpose_cast(
    const float* __restrict__ R, _Float16* __restrict__ Rt)
{
  __shared__ float T[64][65];
  const int j0 = blockIdx.x * 64;
  const int f0 = blockIdx.y * 64;
  const int t = threadIdx.x;
  #pragma unroll
  for (int l = 0; l < 16; ++l) {
    const int idx = t + l * 256;
    T[idx >> 6][idx & 63] = R[(size_t)(j0 + (idx >> 6)) * NF + f0 + (idx & 63)];
  }
  __syncthreads();
  #pragma unroll
  for (int l = 0; l < 16; ++l) {
    const int idx = t + l * 256;
    const int fr = idx >> 6, jc = idx & 63;
    Rt[(size_t)(f0 + fr) * MIND + j0 + jc] = (_Float16)T[jc][fr];
  }
}

__global__ __launch_bounds__(256) void colsum_kernel(
    const float* __restrict__ R, float* __restrict__ cs)
{
  const int b = blockIdx.x;
  const int t = threadIdx.x;
  float s0 = 0.f, s1 = 0.f;
  for (int r = 0; r < 64; ++r) {
    s0 += R[(size_t)(b * 64 + r) * NF + t];
    s1 += R[(size_t)(b * 64 + r) * NF + t + 256];
  }
  atomicAdd(&cs[t], s0); atomicAdd(&cs[t + 256], s1);
}

__global__ __launch_bounds__(256) void var_finalize(
    const float* __restrict__ varacc, const int* __restrict__ mask,
    float* __restrict__ outv)
{
  const int i = blockIdx.x * 256 + threadIdx.x;
  const float m = (mask[i] != 0) ? 1.f : 0.f;
  outv[i] = (1.0f - varacc[i]) * m;
}

}  // namespace

extern "C" void kernel_launch(void* const* d_in, const int* in_sizes, int n_in,
                              void* d_out, int out_size, void* d_ws, size_t ws_size,
                              hipStream_t stream)
{
  (void)in_sizes; (void)n_in; (void)out_size; (void)ws_size;
  const float* x     = (const float*)d_in[0];
  const int*   mask  = (const int*)d_in[1];
  const float* ip    = (const float*)d_in[2];
  const float* gamma = (const float*)d_in[3];
  float* out = (float*)d_out;

  // ---- workspace layout (total ~107.1 MB; R3's passing layout was 119 MB;
  //      R6's failing one was 120.2 MB -> suspected ws overflow) ----
  float* w       = (float*)d_ws;
  float* sum     = w;                     // 512
  float* sumsq   = w + 512;               // 512
  float* cnt     = w + 1024;              // 1 (padded 512)
  float* varacc  = w + 1536;              // 16384
  float* colsumR = w + 17920;             // 512   -> [0, 18432) zeroed
  float* meanv   = w + 18432;
  float* stdv    = w + 18944;
  float* zsv     = w + 19456;
  float* giv     = w + 19968;
  float* rnorm   = w + 20480;             // 16384
  float* cnorm   = w + 36864;             // 2048
  float* u       = w + 38912;             // 2048
  float* Ai      = w + 40960;             // 2048*2048 (Kreg -> Kinv in place)
  float* R       = w + 4235264;           // 2048*512  (written AFTER GJ)
  // GJ scratch aliases R (dead until gemm_f32): 655360 < 1048576 floats
  float* Pall    = R;                     // 32*4096 pivot inverses
  float* Csv     = R + 131072;            // 2 x 2048*64 col-panel slabs
  float* Bsv     = R + 393216;            // 2 x 64*2048 row-panel slabs
  _Float16* hb   = (_Float16*)(w + 5283840);
  _Float16* Zh   = hb;                    // 16384*512 (dead after mfma_gemm<0>)
  _Float16* Kih  = hb;                    // 2048*2048  (aliases Zh, written post-GJ)
  _Float16* Rt   = hb + 4194304;          // 512*2048   (aliases Zh tail)
  _Float16* Zih  = hb + 8388608;          // 2048*512
  _Float16* DK   = hb + 9437184;          // 16384*2048
  // end: hb + 42,991,616 halves = w + 26,779,648 floats = 107.1 MB

  hipMemsetAsync(w, 0, 18432 * sizeof(float), stream);

  stats_kernel<<<256, 256, 0, stream>>>(x, mask, sum, sumsq, cnt);
  finalize_stats<<<2, 256, 0, stream>>>(sum, sumsq, cnt, gamma, meanv, stdv, zsv, giv);
  make_z<<<NROW + MIND, 256, 0, stream>>>(x, mask, ip, meanv, zsv, giv, Zh, Zih, rnorm, cnorm);

  // DK = fp16(exp(-|rn+cn-2 Z Zi^T|) - CC)     [16384 x 2048]  (consumes Zh)
  mfma_gemm<0><<<dim3(MIND / 128, NROW / 128), 256, 0, stream>>>(
      Zh, Zih, NROW, MIND, NF, rnorm, cnorm,
      DK, nullptr, nullptr, nullptr, nullptr, nullptr, nullptr, nullptr, nullptr);
  // Kreg fp32 = exp(-|...|) + 0.05 I           [2048 x 2048]
  mfma_gemm<1><<<dim3(MIND / 128, MIND / 128), 256, 0, stream>>>(
      Zih, Zih, MIND, MIND, NF, cnorm, cnorm,
      nullptr, Ai, nullptr, nullptr, nullptr, nullptr, nullptr, nullptr, nullptr);

  // blocked Gauss-Jordan inverse: 1 boot + 32 independent-step launches
  gj_boot<<<64, 256, 0, stream>>>(Ai, Pall, Csv, Bsv);
  for (int k = 0; k < 32; ++k) {
    float* Cc = Csv + (size_t)(k & 1) * 131072;
    float* Cn = Csv + (size_t)((k + 1) & 1) * 131072;
    float* Bc = Bsv + (size_t)(k & 1) * 131072;
    float* Bn = Bsv + (size_t)((k + 1) & 1) * 131072;
    gj_step<<<512, 256, 0, stream>>>(Ai, Pall, Cc, Bc, Cn, Bn, k);
  }

  // R = Kinv * P (fp32; overwrites GJ scratch region), then derived tensors
  gemm_f32<<<dim3(NF / 64, MIND / 64), 256, 0, stream>>>(Ai, ip, R, MIND, NF, MIND);
  transpose_cast<<<dim3(MIND / 64, NF / 64), 256, 0, stream>>>(R, Rt);
  colsum_kernel<<<MIND / 64, 256, 0, stream>>>(R, colsumR);
  rowsum_kernel<<<MIND / 4, 256, 0, stream>>>(Ai, u);
  cast_half4<<<(MIND * MIND) / 1024, 256, 0, stream>>>(Ai, Kih);

  // varacc_i = sum_j (DK Kinv + CC*1 u^T)_ij * (CC + DK_ij)
  mfma_gemm<2><<<dim3(MIND / 128, NROW / 128), 256, 0, stream>>>(
      DK, Kih, NROW, MIND, MIND, nullptr, nullptr,
      nullptr, nullptr, DK, u, varacc, nullptr, nullptr, nullptr, nullptr);

  // x_new = ((DK Rt^T + CC*colsumR)*std + mean) * mask
  mfma_gemm<3><<<dim3(NF / 128, NROW / 128), 256, 0, stream>>>(
      DK, Rt, NROW, NF, MIND, nullptr, nullptr,
      nullptr, out, nullptr, nullptr, nullptr, colsumR, stdv, meanv, mask);

  var_finalize<<<NROW / 256, 256, 0, stream>>>(varacc, mask, out + (size_t)NROW * NF);
}